// Round 1
// baseline (372.293 us; speedup 1.0000x reference)
//
#include <hip/hip_runtime.h>

namespace {

constexpr int H = 224, W = 224, B = 4, S = 21, R = 5;

__constant__ float c_ang[5] = {-0.5236f, -0.2618f, 0.0f, 0.2618f, 0.5236f};

// One input tap with bounds check (zero padding), accumulating 3 channels.
__device__ __forceinline__ void tap_acc(const float* __restrict__ img,
                                        int x, int y, float wgt,
                                        float& a0, float& a1, float& a2) {
    if ((unsigned)x < (unsigned)W && (unsigned)y < (unsigned)H) {
        const float* p = img + ((y * W + x) * 3);
        a0 = fmaf(wgt, p[0], a0);
        a1 = fmaf(wgt, p[1], a1);
        a2 = fmaf(wgt, p[2], a2);
    }
}

// Stage-1 (shift) sample of the shifted image at integer pixel (X, Y),
// scaled by the stage-2 bilinear weight wgt. Shift in pixels is (tx/2, ty/2),
// axis-aligned (one of tx,ty is 0), so it's a 1- or 2-tap sample.
__device__ __forceinline__ void samp1_acc(const float* __restrict__ img,
                                          int tx, int ty, int X, int Y, float wgt,
                                          float& a0, float& a1, float& a2) {
    int fx2 = 2 * X + tx;          // source coord in half-pixels
    int fy2 = 2 * Y + ty;
    int x0 = fx2 >> 1;             // floor(fx2/2), correct for negatives
    int y0 = fy2 >> 1;
    if (fx2 & 1) {                 // half-pixel in x: two taps, 0.5 each
        tap_acc(img, x0,     y0, wgt * 0.5f, a0, a1, a2);
        tap_acc(img, x0 + 1, y0, wgt * 0.5f, a0, a1, a2);
    } else if (fy2 & 1) {          // half-pixel in y
        tap_acc(img, x0, y0,     wgt * 0.5f, a0, a1, a2);
        tap_acc(img, x0, y0 + 1, wgt * 0.5f, a0, a1, a2);
    } else {                       // integer shift: single tap
        tap_acc(img, x0, y0, wgt, a0, a1, a2);
    }
}

__global__ __launch_bounds__(256) void fused_shift_rotate(
    const float* __restrict__ xs, float* __restrict__ out) {
    int pix = blockIdx.x * 256 + threadIdx.x;
    if (pix >= H * W) return;
    int h = pix / W;
    int w = pix - h * W;
    int b = blockIdx.y;
    int rs = blockIdx.z;           // r*S + s, also the output's leading index
    int r = rs / S;
    int s = rs - r * S;

    // Shift table: up p=1..5, down p=1..5, left p=1..5, right p=1..5 then 0.
    int tx = 0, ty = 0;
    if (s < 5)       ty = s + 1;        // up:    ty = +p
    else if (s < 10) ty = -(s - 4);     // down:  ty = -p
    else if (s < 15) tx = s - 9;        // left:  tx = +p
    else if (s < 20) tx = -(s - 14);    // right: tx = -p
    // s == 20: identity

    float sr, cr;
    sincosf(c_ang[r], &sr, &cr);

    const float cx = 0.5f * (W - 1);
    const float cy = 0.5f * (H - 1);
    float dx = (float)w - cx;
    float dy = (float)h - cy;
    // align_corners=True rotation about image center (H == W so scale = 1)
    float ix = fmaf(dx, cr, fmaf(dy, sr, cx));
    float iy = fmaf(-dx, sr, fmaf(dy, cr, cy));

    float x0f = floorf(ix), y0f = floorf(iy);
    int x0 = (int)x0f, y0 = (int)y0f;
    float wx = ix - x0f, wy = iy - y0f;

    const float* img = xs + (size_t)b * (H * W * 3);

    float a0 = 0.f, a1 = 0.f, a2 = 0.f;
    float w00 = (1.f - wx) * (1.f - wy);
    float w10 = wx * (1.f - wy);
    float w01 = (1.f - wx) * wy;
    float w11 = wx * wy;

    // Stage-2 corners with zero padding: skip loads when the corner is
    // outside the (shifted) image domain — contribution is exactly 0.
    if ((unsigned)x0       < (unsigned)W && (unsigned)y0       < (unsigned)H)
        samp1_acc(img, tx, ty, x0,     y0,     w00, a0, a1, a2);
    if ((unsigned)(x0 + 1) < (unsigned)W && (unsigned)y0       < (unsigned)H)
        samp1_acc(img, tx, ty, x0 + 1, y0,     w10, a0, a1, a2);
    if ((unsigned)x0       < (unsigned)W && (unsigned)(y0 + 1) < (unsigned)H)
        samp1_acc(img, tx, ty, x0,     y0 + 1, w01, a0, a1, a2);
    if ((unsigned)(x0 + 1) < (unsigned)W && (unsigned)(y0 + 1) < (unsigned)H)
        samp1_acc(img, tx, ty, x0 + 1, y0 + 1, w11, a0, a1, a2);

    size_t n = (size_t)rs * B + b;
    float* op = out + ((n * H + h) * W + w) * 3;
    op[0] = a0;
    op[1] = a1;
    op[2] = a2;
}

} // namespace

extern "C" void kernel_launch(void* const* d_in, const int* in_sizes, int n_in,
                              void* d_out, int out_size, void* d_ws, size_t ws_size,
                              hipStream_t stream) {
    const float* xs = (const float*)d_in[0];
    float* out = (float*)d_out;
    dim3 grid((H * W + 255) / 256, B, R * S);
    fused_shift_rotate<<<grid, dim3(256), 0, stream>>>(xs, out);
}

// Round 2
// 282.382 us; speedup vs baseline: 1.3184x; 1.3184x over previous
//
#include <hip/hip_runtime.h>

namespace {

constexpr int H = 224, W = 224, B = 4, S = 21, R = 5;
constexpr int HW = H * W;            // 50176 = 196 * 256, exact grid

// sin/cos of the fixed angles, precomputed (double-accurate literals).
__constant__ float c_sin[5] = {-0.5000010604f, -0.2588196365f, 0.0f,
                                0.2588196365f,  0.5000010604f};
__constant__ float c_cos[5] = { 0.8660247916f,  0.9659256678f, 1.0f,
                                0.9659256678f,  0.8660247916f};

struct alignas(4) f3 { float x, y, z; };   // 12 B, merges to dwordx3

__device__ __forceinline__ float vIn(int x) {   // H == W, one validity helper
    return ((unsigned)x < (unsigned)W) ? 1.0f : 0.0f;
}
__device__ __forceinline__ int clampW(int x) {
    return min(max(x, 0), W - 1);
}
__device__ __forceinline__ void acc3(const f3& t, float wgt,
                                     float& a0, float& a1, float& a2) {
    a0 = fmaf(wgt, t.x, a0);
    a1 = fmaf(wgt, t.y, a1);
    a2 = fmaf(wgt, t.z, a2);
}

__global__ __launch_bounds__(256) void fused_shift_rotate(
    const float* __restrict__ xs, float* __restrict__ out) {
    int pix = blockIdx.x * 256 + threadIdx.x;     // no tail: 196*256 == HW
    int h = pix / W;
    int w = pix - h * W;
    int b = blockIdx.y;
    int rs = blockIdx.z;
    int r = rs / S;
    int s = rs - r * S;

    // Shift table: up p=1..5 (ty=+p), down (ty=-p), left (tx=+p), right (tx=-p), then 0.
    int tx = 0, ty = 0;
    if (s < 5)       ty = s + 1;
    else if (s < 10) ty = -(s - 4);
    else if (s < 15) tx = s - 9;
    else if (s < 20) tx = -(s - 14);

    float sr = c_sin[r], cr = c_cos[r];
    const float cx = 0.5f * (W - 1);
    float dx = (float)w - cx;
    float dy = (float)h - cx;
    // Stage-2 source coordinate (align_corners=True, H == W).
    float ix = fmaf(dy, sr, fmaf(dx, cr, cx));
    float iy = fmaf(dy, cr, fmaf(-dx, sr, cx));

    float x0f = floorf(ix), y0f = floorf(iy);
    int x0 = (int)x0f, y0 = (int)y0f;
    float wx = ix - x0f, wy = iy - y0f;
    float wxl = 1.0f - wx, wyl = 1.0f - wy;

    // Stage-2 corner validity (zero padding).
    float vx0 = vIn(x0), vx1 = vIn(x0 + 1);
    float vy0 = vIn(y0), vy1 = vIn(y0 + 1);

    const f3* img = (const f3*)xs + (size_t)b * HW;

    float a0 = 0.f, a1 = 0.f, a2 = 0.f;

    if (tx & 1) {
        // Half-pixel x shift: footprint 3 cols x 2 rows.
        int xb = (2 * x0 + tx) >> 1;            // leftmost tap column
        // Column weights: stage-1 0.5-taps folded across the two x-corners,
        // times stage-2 x-weights, corner validity, and tap validity.
        float cw0 = 0.5f * wxl * vx0 * vIn(xb);
        float cw1 = 0.5f * (wxl * vx0 + wx * vx1) * vIn(xb + 1);
        float cw2 = 0.5f * wx * vx1 * vIn(xb + 2);
        float rw0 = wyl * vy0;                  // tap row == corner row
        float rw1 = wy * vy1;
        int xc0 = clampW(xb), xc1 = clampW(xb + 1), xc2 = clampW(xb + 2);
        const f3* r0 = img + (size_t)clampW(y0) * W;
        const f3* r1 = img + (size_t)clampW(y0 + 1) * W;
        acc3(r0[xc0], rw0 * cw0, a0, a1, a2);
        acc3(r0[xc1], rw0 * cw1, a0, a1, a2);
        acc3(r0[xc2], rw0 * cw2, a0, a1, a2);
        acc3(r1[xc0], rw1 * cw0, a0, a1, a2);
        acc3(r1[xc1], rw1 * cw1, a0, a1, a2);
        acc3(r1[xc2], rw1 * cw2, a0, a1, a2);
    } else if (ty & 1) {
        // Half-pixel y shift: footprint 2 cols x 3 rows.
        int yb = (2 * y0 + ty) >> 1;
        float rw0 = 0.5f * wyl * vy0 * vIn(yb);
        float rw1 = 0.5f * (wyl * vy0 + wy * vy1) * vIn(yb + 1);
        float rw2 = 0.5f * wy * vy1 * vIn(yb + 2);
        float cw0 = wxl * vx0;
        float cw1 = wx * vx1;
        int xc0 = clampW(x0), xc1 = clampW(x0 + 1);
        const f3* r0 = img + (size_t)clampW(yb) * W;
        const f3* r1 = img + (size_t)clampW(yb + 1) * W;
        const f3* r2 = img + (size_t)clampW(yb + 2) * W;
        acc3(r0[xc0], rw0 * cw0, a0, a1, a2);
        acc3(r0[xc1], rw0 * cw1, a0, a1, a2);
        acc3(r1[xc0], rw1 * cw0, a0, a1, a2);
        acc3(r1[xc1], rw1 * cw1, a0, a1, a2);
        acc3(r2[xc0], rw2 * cw0, a0, a1, a2);
        acc3(r2[xc1], rw2 * cw1, a0, a1, a2);
    } else {
        // Integer shift: footprint 2x2. Tap (x0+i+sx, y0+j+sy); weight needs
        // corner validity AND shifted-tap validity (both separable).
        int sx = tx >> 1, sy = ty >> 1;
        float ax0 = wxl * vx0 * vIn(x0 + sx);
        float ax1 = wx  * vx1 * vIn(x0 + 1 + sx);
        float ay0 = wyl * vy0 * vIn(y0 + sy);
        float ay1 = wy  * vy1 * vIn(y0 + 1 + sy);
        int xc0 = clampW(x0 + sx), xc1 = clampW(x0 + 1 + sx);
        const f3* r0 = img + (size_t)clampW(y0 + sy) * W;
        const f3* r1 = img + (size_t)clampW(y0 + 1 + sy) * W;
        acc3(r0[xc0], ay0 * ax0, a0, a1, a2);
        acc3(r0[xc1], ay0 * ax1, a0, a1, a2);
        acc3(r1[xc0], ay1 * ax0, a0, a1, a2);
        acc3(r1[xc1], ay1 * ax1, a0, a1, a2);
    }

    f3* op = (f3*)out + (size_t)(rs * B + b) * HW + pix;
    f3 v; v.x = a0; v.y = a1; v.z = a2;
    *op = v;
}

} // namespace

extern "C" void kernel_launch(void* const* d_in, const int* in_sizes, int n_in,
                              void* d_out, int out_size, void* d_ws, size_t ws_size,
                              hipStream_t stream) {
    const float* xs = (const float*)d_in[0];
    float* out = (float*)d_out;
    dim3 grid(HW / 256, B, R * S);
    fused_shift_rotate<<<grid, dim3(256), 0, stream>>>(xs, out);
}

// Round 3
// 247.776 us; speedup vs baseline: 1.5025x; 1.1397x over previous
//
#include <hip/hip_runtime.h>

namespace {

constexpr int H = 224, W = 224, B = 4, S = 21, R = 5;
constexpr int HW = H * W;            // 50176 = 196 * 256, exact grid

__constant__ float c_sin[5] = {-0.5000010604f, -0.2588196365f, 0.0f,
                                0.2588196365f,  0.5000010604f};
__constant__ float c_cos[5] = { 0.8660247916f,  0.9659256678f, 1.0f,
                                0.9659256678f,  0.8660247916f};

struct alignas(4) f3 { float x, y, z; };   // 12 B, merges to dwordx3

__device__ __forceinline__ float vIn(int x) {   // H == W
    return ((unsigned)x < (unsigned)W) ? 1.0f : 0.0f;
}
__device__ __forceinline__ int clampW(int x) {
    return min(max(x, 0), W - 1);
}

// One thread = one (r, b, pixel); loops all 21 shifts from a register tile.
__global__ __launch_bounds__(256) void fused_shift_rotate(
    const float* __restrict__ xs, float* __restrict__ out) {
    int pix = blockIdx.x * 256 + threadIdx.x;     // 196*256 == HW, no tail
    int h = pix / W;
    int w = pix - h * W;
    int b = blockIdx.y;
    int r = blockIdx.z;

    float sr = c_sin[r], cr = c_cos[r];
    const float cx = 0.5f * (W - 1);
    float dx = (float)w - cx;
    float dy = (float)h - cx;
    // Stage-2 rotated source coordinate (align_corners=True, H == W).
    float ix = fmaf(dy, sr, fmaf(dx, cr, cx));
    float iy = fmaf(dy, cr, fmaf(-dx, sr, cx));

    float x0f = floorf(ix), y0f = floorf(iy);
    int x0 = (int)x0f, y0 = (int)y0f;
    float wx = ix - x0f, wy = iy - y0f;
    float wxl = 1.0f - wx, wyl = 1.0f - wy;

    float vx0 = vIn(x0), vx1 = vIn(x0 + 1);
    float vy0 = vIn(y0), vy1 = vIn(y0 + 1);
    float rwy0 = wyl * vy0, rwy1 = wy * vy1;   // stage-2 y weights
    float cwx0 = wxl * vx0, cwx1 = wx * vx1;   // stage-2 x weights

    const float* img = xs + (size_t)b * (HW * 3);
    // Output texel for plane n = (r*S+s)*B + b at pixel pix.
    size_t obase = ((size_t)(r * S) * B + b) * (size_t)(HW * 3) + (size_t)pix * 3;
    constexpr size_t splane = (size_t)B * HW * 3;   // +1 in s

    // ---- x-shift group (s = 10..20): taps in rows {y0, y0+1}, cols x0-3..x0+4
    {
        float Hb[2][8][3];
        const float* r0 = img + clampW(y0) * (W * 3);
        const float* r1 = img + clampW(y0 + 1) * (W * 3);
        #pragma unroll
        for (int j = 0; j < 8; ++j) {
            int xc = clampW(x0 - 3 + j) * 3;
            const f3 t0 = *(const f3*)(r0 + xc);
            const f3 t1 = *(const f3*)(r1 + xc);
            Hb[0][j][0] = t0.x; Hb[0][j][1] = t0.y; Hb[0][j][2] = t0.z;
            Hb[1][j][0] = t1.x; Hb[1][j][1] = t1.y; Hb[1][j][2] = t1.z;
        }
        constexpr int tx_tab[11] = {1, 2, 3, 4, 5, -1, -2, -3, -4, -5, 0};
        #pragma unroll
        for (int k = 0; k < 11; ++k) {
            const int tx = tx_tab[k];
            const int s = 10 + k;
            float a[3];
            if (tx & 1) {
                const int j = ((tx - 1) >> 1) + 3;       // compile-time
                int xb = x0 + ((tx - 1) >> 1);
                float cw0 = 0.5f * wxl * vx0 * vIn(xb);
                float cw1 = 0.5f * (wxl * vx0 + wx * vx1) * vIn(xb + 1);
                float cw2 = 0.5f * wx * vx1 * vIn(xb + 2);
                #pragma unroll
                for (int c = 0; c < 3; ++c)
                    a[c] = rwy0 * (cw0 * Hb[0][j][c] + cw1 * Hb[0][j + 1][c] + cw2 * Hb[0][j + 2][c])
                         + rwy1 * (cw0 * Hb[1][j][c] + cw1 * Hb[1][j + 1][c] + cw2 * Hb[1][j + 2][c]);
            } else {
                const int sx = tx >> 1;
                const int j = sx + 3;                    // compile-time
                float ax0 = cwx0 * vIn(x0 + sx);
                float ax1 = cwx1 * vIn(x0 + 1 + sx);
                #pragma unroll
                for (int c = 0; c < 3; ++c)
                    a[c] = rwy0 * (ax0 * Hb[0][j][c] + ax1 * Hb[0][j + 1][c])
                         + rwy1 * (ax0 * Hb[1][j][c] + ax1 * Hb[1][j + 1][c]);
            }
            f3* op = (f3*)(out + obase + (size_t)s * splane);
            f3 v; v.x = a[0]; v.y = a[1]; v.z = a[2];
            *op = v;
        }
    }

    // ---- y-shift group (s = 0..9): taps in cols {x0, x0+1}, rows y0-3..y0+4
    {
        float Vb[8][2][3];
        int xc0 = clampW(x0) * 3, xc1 = clampW(x0 + 1) * 3;
        #pragma unroll
        for (int i = 0; i < 8; ++i) {
            const float* rr = img + clampW(y0 - 3 + i) * (W * 3);
            const f3 t0 = *(const f3*)(rr + xc0);
            const f3 t1 = *(const f3*)(rr + xc1);
            Vb[i][0][0] = t0.x; Vb[i][0][1] = t0.y; Vb[i][0][2] = t0.z;
            Vb[i][1][0] = t1.x; Vb[i][1][1] = t1.y; Vb[i][1][2] = t1.z;
        }
        constexpr int ty_tab[10] = {1, 2, 3, 4, 5, -1, -2, -3, -4, -5};
        #pragma unroll
        for (int k = 0; k < 10; ++k) {
            const int ty = ty_tab[k];
            const int s = k;
            float a[3];
            if (ty & 1) {
                const int i = ((ty - 1) >> 1) + 3;       // compile-time
                int yb = y0 + ((ty - 1) >> 1);
                float rw0 = 0.5f * wyl * vy0 * vIn(yb);
                float rw1 = 0.5f * (wyl * vy0 + wy * vy1) * vIn(yb + 1);
                float rw2 = 0.5f * wy * vy1 * vIn(yb + 2);
                #pragma unroll
                for (int c = 0; c < 3; ++c)
                    a[c] = cwx0 * (rw0 * Vb[i][0][c] + rw1 * Vb[i + 1][0][c] + rw2 * Vb[i + 2][0][c])
                         + cwx1 * (rw0 * Vb[i][1][c] + rw1 * Vb[i + 1][1][c] + rw2 * Vb[i + 2][1][c]);
            } else {
                const int sy = ty >> 1;
                const int i = sy + 3;                    // compile-time
                float ay0 = rwy0 * vIn(y0 + sy);
                float ay1 = rwy1 * vIn(y0 + 1 + sy);
                #pragma unroll
                for (int c = 0; c < 3; ++c)
                    a[c] = cwx0 * (ay0 * Vb[i][0][c] + ay1 * Vb[i + 1][0][c])
                         + cwx1 * (ay0 * Vb[i][1][c] + ay1 * Vb[i + 1][1][c]);
            }
            f3* op = (f3*)(out + obase + (size_t)s * splane);
            f3 v; v.x = a[0]; v.y = a[1]; v.z = a[2];
            *op = v;
        }
    }
}

} // namespace

extern "C" void kernel_launch(void* const* d_in, const int* in_sizes, int n_in,
                              void* d_out, int out_size, void* d_ws, size_t ws_size,
                              hipStream_t stream) {
    const float* xs = (const float*)d_in[0];
    float* out = (float*)d_out;
    dim3 grid(HW / 256, B, R);
    fused_shift_rotate<<<grid, dim3(256), 0, stream>>>(xs, out);
}